// Round 2
// baseline (456.635 us; speedup 1.0000x reference)
//
#include <hip/hip_runtime.h>

// GCNConv: out = scatter_add(norm * (emb[x] @ W^T)[src] -> dst) + b, with self loops.
// N=100000 nodes, D=64, E=1200000 edges. All float32 I/O.

#define N_NODES 100000
#define EDIM    64
#define N_EDGES 1200000

// deg[i] = 1.0 (self loop)
__global__ void k_deg_init(float* __restrict__ deg) {
    int i = blockIdx.x * blockDim.x + threadIdx.x;
    if (i < N_NODES) deg[i] = 1.0f;
}

// deg[dst[e]] += 1
__global__ void k_deg_count(const int* __restrict__ dst, float* __restrict__ deg) {
    int e = blockIdx.x * blockDim.x + threadIdx.x;
    if (e < N_EDGES) atomicAdd(&deg[dst[e]], 1.0f);
}

// deg -> 1/sqrt(deg) in place
__global__ void k_dinv(float* __restrict__ deg) {
    int i = blockIdx.x * blockDim.x + threadIdx.x;
    if (i < N_NODES) deg[i] = rsqrtf(deg[i]);
}

// h[i] = emb[x[i]] @ W^T ; out[i] = b + h[i] * dinv[i]^2   (self-loop term, inits out)
// block = 256 threads = 4 rows x 64 cols. W staged in LDS (padded stride 65 ->
// lanes read Ws[lane*65+k]: bank = (lane+k)&31, all 32 banks, 2-way = free).
__global__ __launch_bounds__(256) void k_gemm(const int* __restrict__ x,
                                              const float* __restrict__ emb,
                                              const float* __restrict__ W,
                                              const float* __restrict__ b,
                                              const float* __restrict__ dinv,
                                              float* __restrict__ h,
                                              float* __restrict__ out) {
    __shared__ float Ws[64 * 65];
    __shared__ float hs[4][64];
    const int tid = threadIdx.x;
    // cooperative load of W (64x64 fp32), row-major W[j][k] -> Ws[j*65+k]
#pragma unroll
    for (int i = 0; i < 16; ++i) {
        int idx = tid + i * 256;
        Ws[(idx >> 6) * 65 + (idx & 63)] = W[idx];
    }
    const int wave = tid >> 6;   // row within block
    const int lane = tid & 63;   // col
    const int row  = blockIdx.x * 4 + wave;
    if (row < N_NODES) {
        int xi = x[row];
        hs[wave][lane] = emb[xi * EDIM + lane];
    }
    __syncthreads();
    if (row < N_NODES) {
        float acc = 0.f;
        const float* wr = &Ws[lane * 65];
#pragma unroll
        for (int k = 0; k < EDIM; ++k) acc += hs[wave][k] * wr[k];
        h[row * EDIM + lane] = acc;
        float di = dinv[row];
        out[row * EDIM + lane] = b[lane] + acc * di * di;
    }
}

// one wave per edge: lane j atomically adds h[src][j]*dinv[src]*dinv[dst] into out[dst][j]
__global__ __launch_bounds__(256) void k_scatter(const int* __restrict__ src,
                                                 const int* __restrict__ dst,
                                                 const float* __restrict__ dinv,
                                                 const float* __restrict__ h,
                                                 float* __restrict__ out) {
    const int tid = threadIdx.x;
    const int e = blockIdx.x * 4 + (tid >> 6);
    const int j = tid & 63;
    if (e < N_EDGES) {
        int s = src[e];
        int d = dst[e];
        float nrm = dinv[s] * dinv[d];
        atomicAdd(&out[d * EDIM + j], h[s * EDIM + j] * nrm);
    }
}

extern "C" void kernel_launch(void* const* d_in, const int* in_sizes, int n_in,
                              void* d_out, int out_size, void* d_ws, size_t ws_size,
                              hipStream_t stream) {
    const int*   x   = (const int*)d_in[0];
    const int*   ei  = (const int*)d_in[1];   // [2, E] flat: src = ei[0:E], dst = ei[E:2E]
    const float* emb = (const float*)d_in[2];
    const float* W   = (const float*)d_in[3];
    const float* b   = (const float*)d_in[4];
    float* out = (float*)d_out;

    // workspace: deg/dinv (N floats) | h (N*64 floats)  => ~26 MB
    float* deg = (float*)d_ws;
    float* h   = deg + N_NODES;

    const int* src = ei;
    const int* dst = ei + N_EDGES;

    k_deg_init<<<(N_NODES + 255) / 256, 256, 0, stream>>>(deg);
    k_deg_count<<<(N_EDGES + 255) / 256, 256, 0, stream>>>(dst, deg);
    k_dinv<<<(N_NODES + 255) / 256, 256, 0, stream>>>(deg);
    k_gemm<<<N_NODES / 4, 256, 0, stream>>>(x, emb, W, b, deg, h, out);
    k_scatter<<<N_EDGES / 4, 256, 0, stream>>>(src, dst, deg, h, out);
}